// Round 15
// baseline (789.987 us; speedup 1.0000x reference)
//
#include <hip/hip_runtime.h>
#include <stdint.h>

typedef unsigned short u16;
typedef __attribute__((ext_vector_type(8))) short short8;
typedef __attribute__((ext_vector_type(4))) float f32x4;

#define NE   8
#define DIN  2048
#define DOUT 8192
#define NTOK 16384

__device__ __forceinline__ u16 f2bf(float f) {
  uint32_t u = __builtin_bit_cast(uint32_t, f);
  u += 0x7FFFu + ((u >> 16) & 1u);   // RNE (inputs are finite normals)
  return (u16)(u >> 16);
}

__global__ __launch_bounds__(256) void cvt_f32_bf16(const float* __restrict__ src,
                                                    u16* __restrict__ dst, size_t n) {
  size_t i = ((size_t)blockIdx.x * 256 + threadIdx.x) * 8;
  const size_t stride = (size_t)gridDim.x * 256 * 8;
  for (; i < n; i += stride) {
    f32x4 a = *(const f32x4*)(src + i);
    f32x4 b = *(const f32x4*)(src + i + 4);
    short8 o;
    o[0] = (short)f2bf(a[0]); o[1] = (short)f2bf(a[1]);
    o[2] = (short)f2bf(a[2]); o[3] = (short)f2bf(a[3]);
    o[4] = (short)f2bf(b[0]); o[5] = (short)f2bf(b[1]);
    o[6] = (short)f2bf(b[2]); o[7] = (short)f2bf(b[3]);
    *(short8*)(dst + i) = o;
  }
}

#define GLOAD_LDS16(g, l) __builtin_amdgcn_global_load_lds( \
    (const __attribute__((address_space(1))) void*)(g),     \
    (__attribute__((address_space(3))) void*)(l), 16, 0, 0)

// ---------------------------------------------------------------------------
// r15: TLP attack. r11/r14's intra-block schedule is at a 10-round-verified
// plateau; Occupancy ~22% shows 1 block/CU, 2 waves/SIMD — barrier stalls
// have no independent filler. This round: tile 256x128, BK=32, wave=64x64
// (acc 4x4 = 64 regs -> ~128/wave total), LDS 48KB, __launch_bounds__(512,4)
// => 2 INDEPENDENT blocks/CU (16 waves, 4/SIMD): one block's barrier/lgkm
// stalls are filled by the other's MFMA (m114/m97 evidence).
// Per K-tile (2 barriers, verified idioms only):
//   [8 ds_reads(cur, published); LGKM0; BAR1;
//    stage t+2 -> cur (3 gloads; safe: BAR1 proves all waves' reads done);
//    16 MFMA; VMW(3) (queue 6 = t+1,t+2 -> drains t+1); BAR2 = publish t+1]
// Tail (r2 lesson): t+2>=NKT -> skip stage, VMW(0) if t+1 exists; last: none.
// Staging/read swizzle byte-identical to the measured-0-conflict r3 pattern
// (layout is [rows][32k] slices either way). Epilogue = r11's coalesced
// LDS-repack (single-buffered scratch, 34.8KB <= 48KB).
// ---------------------------------------------------------------------------
__global__ __launch_bounds__(512, 4) void moe_gemm8(
    const u16* __restrict__ Xb, const u16* __restrict__ Wb,
    const int* __restrict__ counts, const float* __restrict__ bias,
    float* __restrict__ C) {
  extern __shared__ u16 sm[];  // 24576 u16 = 48 KiB

  const int tid = threadIdx.x;
  const int l = tid & 63;
  const int wid = tid >> 6;      // 0..7
  const int wr = wid >> 1;       // 0..3  (M quarters of 64)
  const int wc = wid & 1;        // 0..1  (N halves of 64)

  // XCD-bijective swizzle: 4096 blocks, 512/XCD == tiles/expert => expert==XCD
  const int id = blockIdx.x;
  const int swz = (id & 7) * 512 + (id >> 3);
  const int e = swz >> 9;
  const int rem = swz & 511;
  const int tn = rem >> 3;       // 0..63 (8 consecutive blocks share W-panel)
  const int tm = rem & 7;        // 0..7

  int off = 0;
  for (int i = 0; i < e; ++i) off += counts[i];
  const int row0 = off + tm * 256;
  const int col0 = tn * 128;
  const size_t wbase = (size_t)e * DOUT * DIN + (size_t)col0 * DIN;

  // -- staging per-lane constants (pre-swizzled global source, linear dest)
  const int rl = l >> 2;                     // row within 16-row slice
  const int q = (l & 3) ^ ((l >> 3) & 3);    // source k-granule (inverse swz)
  const int s0 = wid * 2, s1 = s0 + 1;       // A: 2 slices of 16 (rows 0..255)
  const u16* pA0 = Xb + (size_t)(row0 + s0 * 16 + rl) * DIN + q * 8;
  const u16* pA1 = Xb + (size_t)(row0 + s1 * 16 + rl) * DIN + q * 8;
  const u16* pB0 = Wb + wbase + (size_t)(wid * 16 + rl) * DIN + q * 8;  // B: 1 slice

  // -- fragment-read per-lane constants (16x16 layout, r3-verified swizzle)
  const int gph = (l >> 4) ^ (((l & 15) >> 1) & 3);   // physical granule
  const int aoff = (wr * 64 + (l & 15)) * 32 + gph * 8;
  const int boff = (wc * 64 + (l & 15)) * 32 + gph * 8;

  f32x4 acc[4][4] = {};
  short8 a[4], b[4];

#define SMA(buf) (sm + (buf) * 8192)            // A: [2][256][32] u16
#define SMB(buf) (sm + 16384 + (buf) * 4096)    // B: [2][128][32] u16
#define STAGE(buf, kt) do { const int ko = (kt) * 32;      \
    GLOAD_LDS16(pA0 + ko, SMA(buf) + s0 * 512);            \
    GLOAD_LDS16(pA1 + ko, SMA(buf) + s1 * 512);            \
    GLOAD_LDS16(pB0 + ko, SMB(buf) + wid * 512); } while (0)
#define RA4(buf) do { _Pragma("unroll") for (int mf = 0; mf < 4; ++mf) \
    a[mf] = *(const short8*)(SMA(buf) + aoff + mf * 512); } while (0)
#define RB4(buf) do { _Pragma("unroll") for (int nf = 0; nf < 4; ++nf) \
    b[nf] = *(const short8*)(SMB(buf) + boff + nf * 512); } while (0)
#define FENCE() asm volatile("" ::: "memory")
#define BAR() do { FENCE(); __builtin_amdgcn_s_barrier(); FENCE(); } while (0)
#define VMW(N) asm volatile("s_waitcnt vmcnt(" #N ")" ::: "memory")
#define LGKM0() asm volatile("s_waitcnt lgkmcnt(0)" ::: "memory")
#define MM16() do { __builtin_amdgcn_s_setprio(1);                                 \
    _Pragma("unroll") for (int mf = 0; mf < 4; ++mf)                               \
      _Pragma("unroll") for (int nf = 0; nf < 4; ++nf)                             \
        acc[mf][nf] =                                                              \
          __builtin_amdgcn_mfma_f32_16x16x32_bf16(a[mf], b[nf], acc[mf][nf], 0, 0, 0); \
    __builtin_amdgcn_s_setprio(0); } while (0)

  const int NKT = DIN / 32;  // 64 K-tiles

  // prologue: stage t0 (3 loads) + t1 (3); VMW(3) drains t0 exactly; publish.
  STAGE(0, 0); STAGE(1, 1);
  VMW(3);
  BAR();

  for (int kt = 0; kt < NKT; kt += 2) {
#define TILE(cur, nxt, t) do {                                          \
    const bool h1 = (t) + 1 < NKT;                                      \
    const bool h2 = (t) + 2 < NKT;                                      \
    /* reads of cur (published at prior BAR2) */                        \
    RA4(cur); RB4(cur);                                                 \
    LGKM0(); BAR();   /* BAR1: all waves' reads of cur complete */      \
    if (h2) STAGE(cur, (t) + 2);   /* overwrite cur: safe post-BAR1 */  \
    MM16();                                                             \
    if (h2) VMW(3);   /* queue 6 = {t+1,t+2}: drain t+1 */              \
    else if (h1) VMW(0);  /* tail: counted wait would no-op (r2) */     \
    BAR();            /* BAR2: publish t+1 */                           \
    } while (0)
    TILE(0, 1, kt);
    TILE(1, 0, kt + 1);
#undef TILE
  }

  // ---- epilogue: LDS repack -> coalesced nontemporal dwordx4 stores ----
  // (LDS free after K-loop; per-wave 16x68 f32 scratch, single-buffered)
  float* smf = (float*)sm;
  const int cbw = col0 + wc * 64;             // wave's 64-col span
  const int r0 = (l >> 4) << 2;               // acc row offset within frag
  const f32x4 bv4 = *(const f32x4*)(bias + (size_t)e * DOUT + cbw + (l & 15) * 4);
  float* eb = smf + wid * 1088;               // 16x68 f32 per wave

#pragma unroll
  for (int m = 0; m < 4; ++m) {
    if (m) LGKM0();   // WAR: prior readback of eb complete before overwrite
#pragma unroll
    for (int n = 0; n < 4; ++n) {
      const int c = n * 16 + (l & 15);
#pragma unroll
      for (int j = 0; j < 4; ++j)
        eb[(r0 + j) * 68 + c] = acc[m][n][j];
    }
    LGKM0();  // own writes visible (wave-private region)
    const int rbm = row0 + wr * 64 + m * 16;
#pragma unroll
    for (int i = 0; i < 4; ++i) {
      const int row = i * 4 + (l >> 4);
      f32x4 v = *(const f32x4*)(eb + row * 68 + (l & 15) * 4);
      v = v + bv4;
      __builtin_nontemporal_store(
          v, (f32x4*)(C + (size_t)(rbm + row) * DOUT + cbw + (l & 15) * 4));
    }
  }
}

// ---------------------------------------------------------------------------
// Fallback (ws too small): fused fp32->bf16 staging, 128x128 m97 structure.
// ---------------------------------------------------------------------------
__global__ __launch_bounds__(256) void moe_gemm_fused(
    const float* __restrict__ Xf, const float* __restrict__ Wf,
    const int* __restrict__ counts, const float* __restrict__ bias,
    float* __restrict__ C) {
  __shared__ __align__(16) u16 lds[2][2][128 * 32];

  const int tid = threadIdx.x;
  const int lane = tid & 63;
  const int wid = tid >> 6;
  const int wr = wid >> 1;
  const int wc = wid & 1;

  const int id = blockIdx.x;
  const int swz = (id & 7) * ((int)gridDim.x >> 3) + (id >> 3);
  const int e = swz >> 10;
  const int rem = swz & 1023;
  const int tn = rem >> 4;
  const int tml = rem & 15;

  int off = 0;
  for (int i = 0; i < e; ++i) off += counts[i];
  const int row0 = off + tml * 128;
  const int col0 = tn * 128;
  const size_t wbase = (size_t)e * DOUT * DIN + (size_t)col0 * DIN;

  f32x4 acc[4][4] = {};

  auto stage = [&](int buf, int kt) {
#pragma unroll
    for (int s = 0; s < 2; ++s) {
      int i = s * 256 + tid;
      int r = i >> 2, c = i & 3;
      const float* sa = Xf + (size_t)(row0 + r) * DIN + kt * 32 + c * 8;
      const float* sb = Wf + wbase + (size_t)r * DIN + kt * 32 + c * 8;
      f32x4 a0 = *(const f32x4*)sa;
      f32x4 a1 = *(const f32x4*)(sa + 4);
      f32x4 b0 = *(const f32x4*)sb;
      f32x4 b1 = *(const f32x4*)(sb + 4);
      short8 va, vb;
#pragma unroll
      for (int j = 0; j < 4; ++j) {
        va[j] = (short)f2bf(a0[j]); va[j + 4] = (short)f2bf(a1[j]);
        vb[j] = (short)f2bf(b0[j]); vb[j + 4] = (short)f2bf(b1[j]);
      }
      *(short8*)&lds[buf][0][i * 8] = va;
      *(short8*)&lds[buf][1][i * 8] = vb;
    }
  };

  auto compute = [&](int buf) {
    const int kc = lane >> 4;
    const int rr = lane & 15;
    short8 a[4], b[4];
    const u16* lA = lds[buf][0];
    const u16* lB = lds[buf][1];
#pragma unroll
    for (int m = 0; m < 4; ++m)
      a[m] = *(const short8*)(lA + (wr * 64 + m * 16 + rr) * 32 + kc * 8);
#pragma unroll
    for (int n = 0; n < 4; ++n)
      b[n] = *(const short8*)(lB + (wc * 64 + n * 16 + rr) * 32 + kc * 8);
#pragma unroll
    for (int m = 0; m < 4; ++m)
#pragma unroll
      for (int n = 0; n < 4; ++n)
        acc[m][n] = __builtin_amdgcn_mfma_f32_16x16x32_bf16(a[m], b[n], acc[m][n], 0, 0, 0);
  };

  stage(0, 0);
  for (int kt = 0; kt < DIN / 32; ++kt) {
    __syncthreads();
    if (kt + 1 < DIN / 32) stage((kt + 1) & 1, kt + 1);
    compute(kt & 1);
  }

  const int rbase = row0 + wr * 64;
  const int cbase = col0 + wc * 64;
#pragma unroll
  for (int n = 0; n < 4; ++n) {
    const int col = cbase + n * 16 + (lane & 15);
    const float bv = bias[e * DOUT + col];
#pragma unroll
    for (int m = 0; m < 4; ++m) {
      const int r0 = rbase + m * 16 + (lane >> 4) * 4;
#pragma unroll
      for (int j = 0; j < 4; ++j)
        C[(size_t)(r0 + j) * DOUT + col] = acc[m][n][j] + bv;
    }
  }
}

extern "C" void kernel_launch(void* const* d_in, const int* in_sizes, int n_in,
                              void* d_out, int out_size, void* d_ws, size_t ws_size,
                              hipStream_t stream) {
  const float* inp = (const float*)d_in[0];
  const int* counts = (const int*)d_in[1];
  const float* weight = (const float*)d_in[2];
  const float* bias = (const float*)d_in[3];
  float* out = (float*)d_out;

  const size_t nx = (size_t)NTOK * DIN;
  const size_t nw = (size_t)NE * DOUT * DIN;
  const size_t need = (nx + nw) * sizeof(u16);

  if (ws_size >= need) {
    u16* xb = (u16*)d_ws;
    u16* wb = xb + nx;
    cvt_f32_bf16<<<2048, 256, 0, stream>>>(inp, xb, nx);
    cvt_f32_bf16<<<4096, 256, 0, stream>>>(weight, wb, nw);
    const int grid = (NTOK / 256) * (DOUT / 128);  // 4096
    moe_gemm8<<<grid, 512, 49152, stream>>>(xb, wb, counts, bias, out);
  } else {
    const int grid = (NTOK / 128) * (DOUT / 128);  // 8192
    moe_gemm_fused<<<grid, 256, 0, stream>>>(inp, weight, counts, bias, out);
  }
}